// Round 9
// baseline (94.064 us; speedup 1.0000x reference)
//
#include <hip/hip_runtime.h>

typedef short bf16x8 __attribute__((ext_vector_type(8)));
typedef float f32x4 __attribute__((ext_vector_type(4)));
typedef float f32x16 __attribute__((ext_vector_type(16)));
typedef unsigned u32x4 __attribute__((ext_vector_type(4)));

#define SWZ(r, cb) ((((int)(r)) << 7) + (((int)(cb)) ^ ((((int)(r)) & 7) << 4)))

__device__ __forceinline__ unsigned short f2b(float f) {
    unsigned u = __builtin_bit_cast(unsigned, f);
    u = (u + 0x7FFFu + ((u >> 16) & 1u)) >> 16;
    return (unsigned short)u;
}
__device__ __forceinline__ float b2f(unsigned short h) {
    unsigned u = ((unsigned)h) << 16;
    return __builtin_bit_cast(float, u);
}
__device__ __forceinline__ void gload16(void* lds, const void* gsrc) {
    __builtin_amdgcn_global_load_lds((const __attribute__((address_space(1))) void*)gsrc,
                                     (__attribute__((address_space(3))) void*)lds, 16, 0, 0);
}

// ---------------- LayerNorm: one wave per token, H=768 ----------------
__global__ __launch_bounds__(256) void ln_kernel(const float* __restrict__ x,
                                                 const float* __restrict__ gamma,
                                                 const float* __restrict__ beta,
                                                 unsigned short* __restrict__ h) {
    int lane = threadIdx.x & 63, wv = threadIdx.x >> 6;
    int tok = blockIdx.x * 4 + wv;
    const float* xr = x + (size_t)tok * 768;
    float v[12];
#pragma unroll
    for (int c = 0; c < 3; c++) {
        float4 t = *(const float4*)(xr + c * 256 + lane * 4);
        v[c * 4 + 0] = t.x; v[c * 4 + 1] = t.y; v[c * 4 + 2] = t.z; v[c * 4 + 3] = t.w;
    }
    float s = 0.f;
#pragma unroll
    for (int j = 0; j < 12; j++) s += v[j];
#pragma unroll
    for (int m = 1; m < 64; m <<= 1) s += __shfl_xor(s, m, 64);
    float mu = s * (1.0f / 768.0f);
    float s2 = 0.f;
#pragma unroll
    for (int j = 0; j < 12; j++) { float d = v[j] - mu; s2 += d * d; }
#pragma unroll
    for (int m = 1; m < 64; m <<= 1) s2 += __shfl_xor(s2, m, 64);
    float rstd = 1.0f / sqrtf(s2 * (1.0f / 768.0f) + 1e-12f);
    unsigned short* hr = h + (size_t)tok * 768;
#pragma unroll
    for (int c = 0; c < 3; c++) {
        float4 g = *(const float4*)(gamma + c * 256 + lane * 4);
        float4 bt = *(const float4*)(beta + c * 256 + lane * 4);
        ushort4 o;
        o.x = f2b((v[c * 4 + 0] - mu) * rstd * g.x + bt.x);
        o.y = f2b((v[c * 4 + 1] - mu) * rstd * g.y + bt.y);
        o.z = f2b((v[c * 4 + 2] - mu) * rstd * g.z + bt.z);
        o.w = f2b((v[c * 4 + 3] - mu) * rstd * g.w + bt.w);
        *(ushort4*)(hr + c * 256 + lane * 4) = o;
    }
}

// ---------------- Weight transpose+convert: fp32 [K][N] -> bf16 [N][K], K=768 ----------------
__global__ __launch_bounds__(256) void transw_kernel(const float* __restrict__ Wq,
                                                     const float* __restrict__ Wk,
                                                     const float* __restrict__ Wv,
                                                     const float* __restrict__ Wo,
                                                     unsigned short* __restrict__ WqT,
                                                     unsigned short* __restrict__ WkT,
                                                     unsigned short* __restrict__ WvT,
                                                     unsigned short* __restrict__ WoT) {
    __shared__ float tile[64][65];
    const float* W; unsigned short* WT; int N;
    switch (blockIdx.z) {
        case 0:  W = Wq; WT = WqT; N = 768; break;
        case 1:  W = Wk; WT = WkT; N = 256; break;
        case 2:  W = Wv; WT = WvT; N = 256; break;
        default: W = Wo; WT = WoT; N = 768; break;
    }
    int n0 = blockIdx.x * 64, k0 = blockIdx.y * 64;
    if (n0 >= N) return;
    int t = threadIdx.x;
#pragma unroll
    for (int i = 0; i < 4; i++) {
        int kr = (t >> 4) + i * 16, nc = (t & 15) * 4;
        float4 f = *(const float4*)(W + (size_t)(k0 + kr) * N + n0 + nc);
        tile[kr][nc + 0] = f.x; tile[kr][nc + 1] = f.y;
        tile[kr][nc + 2] = f.z; tile[kr][nc + 3] = f.w;
    }
    __syncthreads();
#pragma unroll
    for (int i = 0; i < 2; i++) {
        int nr = (t >> 3) + i * 32, kc = (t & 7) * 8;
        bf16x8 o;
#pragma unroll
        for (int j = 0; j < 8; j++) o[j] = (short)f2b(tile[kc + j][nr]);
        *(bf16x8*)(WT + (size_t)(n0 + nr) * 768 + k0 + kc) = o;
    }
}

// ---- QKV GEMM: 128x128 tile, gload_lds dbuf; epilogue: Q plain, K+RoPE->kfrag, V->vfrag ----
__global__ __launch_bounds__(256) void gemm_qkv(const unsigned short* __restrict__ A,
                                                const unsigned short* __restrict__ WqT,
                                                const unsigned short* __restrict__ WkT,
                                                const unsigned short* __restrict__ WvT,
                                                const float* __restrict__ bq,
                                                const float* __restrict__ bk,
                                                const float* __restrict__ bv,
                                                unsigned short* __restrict__ qo,
                                                unsigned short* __restrict__ kfrag,
                                                unsigned short* __restrict__ vfrag) {
    __shared__ __align__(1024) char smem[65536];
    const int m0 = blockIdx.x * 128;
    const int n0 = blockIdx.y * 128;
    const unsigned short* WT; const float* bias; int c0;
    if (n0 < 768)       { WT = WqT + (size_t)n0 * 768;          bias = bq; c0 = n0;        }
    else if (n0 < 1024) { WT = WkT + (size_t)(n0 - 768) * 768;  bias = bk; c0 = n0 - 768;  }
    else                { WT = WvT + (size_t)(n0 - 1024) * 768; bias = bv; c0 = n0 - 1024; }
    const int tid = threadIdx.x, lane = tid & 63, w = tid >> 6;
    const int wr = w >> 1, wc = w & 1;
    const int l15 = lane & 15;
    const int rl = lane >> 3, cl = lane & 7;
    const int scol = (cl * 16) ^ (rl << 4);

    const char* srcA0 = (const char*)A  + (size_t)(m0 + w * 32 +  0 + rl) * 1536 + scol;
    const char* srcA1 = (const char*)A  + (size_t)(m0 + w * 32 +  8 + rl) * 1536 + scol;
    const char* srcA2 = (const char*)A  + (size_t)(m0 + w * 32 + 16 + rl) * 1536 + scol;
    const char* srcA3 = (const char*)A  + (size_t)(m0 + w * 32 + 24 + rl) * 1536 + scol;
    const char* srcB0 = (const char*)WT + (size_t)(w * 32 +  0 + rl) * 1536 + scol;
    const char* srcB1 = (const char*)WT + (size_t)(w * 32 +  8 + rl) * 1536 + scol;
    const char* srcB2 = (const char*)WT + (size_t)(w * 32 + 16 + rl) * 1536 + scol;
    const char* srcB3 = (const char*)WT + (size_t)(w * 32 + 24 + rl) * 1536 + scol;
    const int cb = w * 4096;

    f32x4 acc[4][4];
#pragma unroll
    for (int m = 0; m < 4; m++)
#pragma unroll
        for (int n = 0; n < 4; n++) acc[m][n] = (f32x4){0.f, 0.f, 0.f, 0.f};

    gload16(smem + cb +    0, srcA0); gload16(smem + cb + 1024, srcA1);
    gload16(smem + cb + 2048, srcA2); gload16(smem + cb + 3072, srcA3);
    gload16(smem + 32768 + cb +    0, srcB0); gload16(smem + 32768 + cb + 1024, srcB1);
    gload16(smem + 32768 + cb + 2048, srcB2); gload16(smem + 32768 + cb + 3072, srcB3);
    __syncthreads();

    for (int t = 0; t < 12; ++t) {
        const int cur = t & 1;
        if (t < 11) {
            srcA0 += 128; srcA1 += 128; srcA2 += 128; srcA3 += 128;
            srcB0 += 128; srcB1 += 128; srcB2 += 128; srcB3 += 128;
            char* ab = smem + (cur ^ 1) * 16384 + cb;
            char* bb = smem + 32768 + (cur ^ 1) * 16384 + cb;
            gload16(ab +    0, srcA0); gload16(ab + 1024, srcA1);
            gload16(ab + 2048, srcA2); gload16(ab + 3072, srcA3);
            gload16(bb +    0, srcB0); gload16(bb + 1024, srcB1);
            gload16(bb + 2048, srcB2); gload16(bb + 3072, srcB3);
        }
        const char* Ab = smem + cur * 16384;
        const char* Bb = smem + 32768 + cur * 16384;
#pragma unroll
        for (int ks = 0; ks < 2; ks++) {
            bf16x8 a[4], b[4];
#pragma unroll
            for (int m = 0; m < 4; m++)
                a[m] = *(const bf16x8*)(Ab + SWZ(wr * 64 + m * 16 + l15, (lane >> 4) * 16 + ks * 64));
#pragma unroll
            for (int n = 0; n < 4; n++)
                b[n] = *(const bf16x8*)(Bb + SWZ(wc * 64 + n * 16 + l15, (lane >> 4) * 16 + ks * 64));
#pragma unroll
            for (int m = 0; m < 4; m++)
#pragma unroll
                for (int n = 0; n < 4; n++)
                    acc[m][n] = __builtin_amdgcn_mfma_f32_16x16x32_bf16(a[m], b[n], acc[m][n], 0, 0, 0);
        }
        __syncthreads();
    }

    if (n0 >= 1024) {
        // V: bias + store into vfrag fragment layout
#pragma unroll
        for (int n = 0; n < 4; n++) {
            int col = c0 + wc * 64 + n * 16 + l15;
            float bs = bias[col];
            int g = col >> 6, d = col & 63;
            int hd = d >> 5, ld = d & 31;
#pragma unroll
            for (int m = 0; m < 4; m++) {
                int row = m0 + wr * 64 + m * 16 + ((lane >> 4) << 2);
                int bb2 = row >> 11, srow = row & 2047;
                int tt = srow >> 6, kvc = srow & 63;
                int s = kvc >> 4, hl = (kvc >> 3) & 1, j0 = kvc & 7;
                ushort4 o;
                o.x = f2b(acc[m][n][0] + bs); o.y = f2b(acc[m][n][1] + bs);
                o.z = f2b(acc[m][n][2] + bs); o.w = f2b(acc[m][n][3] + bs);
                *(ushort4*)((char*)vfrag + ((size_t)((bb2 * 4 + g) * 32 + tt)) * 8192 +
                            (2 * s + hd) * 1024 + (hl * 32 + ld) * 16 + j0 * 2) = o;
            }
        }
    } else if (n0 >= 768) {
        // K: bias + RoPE, store into kfrag fragment layout
#pragma unroll
        for (int n = 0; n < 2; n++) {
            int col = c0 + wc * 64 + n * 16 + l15;
            float bs1 = bias[col], bs2 = bias[col + 32];
            int g = col >> 6, i = col & 63;   // i < 32
            float freq = exp2f(-(float)i * (13.287712379549449f / 32.0f));
            int s = i >> 4, h2k = (i >> 3) & 1, j = i & 7;
            int laneoff = (h2k * 32 + 0) * 16 + j * 2;
#pragma unroll
            for (int m = 0; m < 4; m++) {
#pragma unroll
                for (int r = 0; r < 4; r++) {
                    int row = m0 + wr * 64 + m * 16 + ((lane >> 4) << 2) + r;
                    int bb2 = row >> 11, srow = row & 2047;
                    int tt = srow >> 6, kvr = srow & 63, hk = kvr >> 5, lkv = kvr & 31;
                    float sn, cs;
                    sincosf((float)srow * freq, &sn, &cs);
                    float x1 = acc[m][n][r] + bs1, x2 = acc[m][n + 2][r] + bs2;
                    size_t base = ((size_t)((bb2 * 4 + g) * 32 + tt)) * 8192 + laneoff + lkv * 16;
                    *(unsigned short*)((char*)kfrag + base + (2 * s + hk) * 1024)     = f2b(x1 * cs - x2 * sn);
                    *(unsigned short*)((char*)kfrag + base + (2 * s + 4 + hk) * 1024) = f2b(x1 * sn + x2 * cs);
                }
            }
        }
    } else {
        // Q: plain bias store (RoPE+scale applied in flash)
#pragma unroll
        for (int n = 0; n < 4; n++) {
            int col = c0 + wc * 64 + n * 16 + l15;
            float bs = bias[col];
#pragma unroll
            for (int m = 0; m < 4; m++) {
#pragma unroll
                for (int r = 0; r < 4; r++) {
                    int row = m0 + wr * 64 + m * 16 + ((lane >> 4) << 2) + r;
                    qo[(size_t)row * 768 + col] = f2b(acc[m][n][r] + bs);
                }
            }
        }
    }
}

// ---- Flash attention: 4 waves (2 qsub x 2 KV-halves), 3 heads per wave, static-C softmax ----
__global__ __launch_bounds__(256, 1) void flash4_kernel(const unsigned short* __restrict__ qb,
                                                        const unsigned short* __restrict__ kfrag,
                                                        const unsigned short* __restrict__ vfrag,
                                                        unsigned short* __restrict__ ob) {
    __shared__ __align__(1024) char smem[65536];
    const int s0 = blockIdx.x * 64;
    const int bg = blockIdx.y, b = bg >> 2;
    const int tid = threadIdx.x, lane = tid & 63, w = tid >> 6;
    const int h2 = lane >> 5, l31 = lane & 31;
    const int qsub = w >> 1, half = w & 1;
    const int hbase = (bg & 3) * 3;

    // staging: 32 chunk-slots, 8 per wave (c = w + 4i); slot c: hf=c>>4, cc=c&15 (<8 K, else V)
    const char* kf = (const char*)kfrag + (size_t)bg * 262144;
    const char* vf = (const char*)vfrag + (size_t)bg * 262144;
    const char* srcs[8]; int ldss[8];
#pragma unroll
    for (int i = 0; i < 8; i++) {
        int c = w + i * 4;
        int hf = c >> 4, cc = c & 15;
        const char* basep = (cc < 8) ? kf : vf;
        srcs[i] = basep + (size_t)(hf * 16) * 8192 + (cc & 7) * 1024 + lane * 16;
        ldss[i] = hf * 32768 + ((cc < 8) ? 0 : 16384) + (cc & 7) * 1024;
    }
#pragma unroll
    for (int i = 0; i < 8; i++) gload16(smem + ldss[i], srcs[i]);

    // Q for 3 heads: RoPE + 1/8*log2e scale in-register
    const int qrow = s0 + qsub * 32 + l31;
    bf16x8 qf[3][4];
    {
        const float SC = 0.125f * 1.4426950408889634f;
        float cs_[16], sn_[16];
#pragma unroll
        for (int s = 0; s < 2; s++)
#pragma unroll
            for (int j = 0; j < 8; j++) {
                int i = 16 * s + 8 * h2 + j;
                float freq = exp2f(-(float)i * (13.287712379549449f / 32.0f));
                sincosf((float)qrow * freq, &sn_[s * 8 + j], &cs_[s * 8 + j]);
            }
#pragma unroll
        for (int u = 0; u < 3; u++) {
            const unsigned short* qbase = qb + ((size_t)(b * 2048 + qrow) * 12 + hbase + u) * 64 + 8 * h2;
            bf16x8 q0 = *(const bf16x8*)(qbase);
            bf16x8 q1 = *(const bf16x8*)(qbase + 16);
            bf16x8 q2 = *(const bf16x8*)(qbase + 32);
            bf16x8 q3 = *(const bf16x8*)(qbase + 48);
#pragma unroll
            for (int j = 0; j < 8; j++) {
                float x1 = b2f((unsigned short)q0[j]), x2 = b2f((unsigned short)q2[j]);
                qf[u][0][j] = (short)f2b((x1 * cs_[j] - x2 * sn_[j]) * SC);
                qf[u][2][j] = (short)f2b((x1 * sn_[j] + x2 * cs_[j]) * SC);
                float y1 = b2f((unsigned short)q1[j]), y2 = b2f((unsigned short)q3[j]);
                qf[u][1][j] = (short)f2b((y1 * cs_[8 + j] - y2 * sn_[8 + j]) * SC);
                qf[u][3][j] = (short)f2b((y1 * sn_[8 + j] + y2 * cs_[8 + j]) * SC);
            }
        }
    }

    f32x16 acc[3][2], cinit;
#pragma unroll
    for (int u = 0; u < 3; u++)
#pragma unroll
        for (int k = 0; k < 2; k++)
#pragma unroll
            for (int r = 0; r < 16; r++) acc[u][k][r] = 0.f;
#pragma unroll
    for (int r = 0; r < 16; r++) cinit[r] = -24.0f;
    float lr0 = 0.f, lr1 = 0.f, lr2 = 0.f;

    __syncthreads();

#define SUM16(V) (((((V)[0]+(V)[1])+((V)[2]+(V)[3]))+(((V)[4]+(V)[5])+((V)[6]+(V)[7]))) + \
                  ((((V)[8]+(V)[9])+((V)[10]+(V)[11]))+(((V)[12]+(V)[13])+((V)[14]+(V)[15]))))

    for (int t = 0; t < 16; ++t) {
        const int cur = t & 1;
        if (t < 15) {
            const int nb = (cur ^ 1) * 8192;
#pragma unroll
            for (int i = 0; i < 8; i++) { srcs[i] += 8192; gload16(smem + ldss[i] + nb, srcs[i]); }
        }
        const char* kb_ = smem + half * 32768 + cur * 8192 + lane * 16;
        const char* vb_ = kb_ + 16384;

#pragma unroll
        for (int kvb = 0; kvb < 2; kvb++) {
            // S - 24 = K x Q^T for 3 heads, sharing each K-fragment read
            f32x16 s0c, s1c, s2c;
            __builtin_amdgcn_s_setprio(1);
            {
                bf16x8 ak = *(const bf16x8*)(kb_ + kvb * 1024);
                s0c = __builtin_amdgcn_mfma_f32_32x32x16_bf16(ak, qf[0][0], cinit, 0, 0, 0);
                s1c = __builtin_amdgcn_mfma_f32_32x32x16_bf16(ak, qf[1][0], cinit, 0, 0, 0);
                s2c = __builtin_amdgcn_mfma_f32_32x32x16_bf16(ak, qf[2][0], cinit, 0, 0, 0);
            }
#pragma unroll
            for (int s = 1; s < 4; s++) {
                bf16x8 ak = *(const bf16x8*)(kb_ + s * 2048 + kvb * 1024);
                s0c = __builtin_amdgcn_mfma_f32_32x32x16_bf16(ak, qf[0][s], s0c, 0, 0, 0);
                s1c = __builtin_amdgcn_mfma_f32_32x32x16_bf16(ak, qf[1][s], s1c, 0, 0, 0);
                s2c = __builtin_amdgcn_mfma_f32_32x32x16_bf16(ak, qf[2][s], s2c, 0, 0, 0);
            }
            __builtin_amdgcn_s_setprio(0);

            // P = exp2(S-24); accumulate per-lane partial l (cross-lane deferred)
#pragma unroll
            for (int r = 0; r < 16; r++) s0c[r] = __builtin_amdgcn_exp2f(s0c[r]);
#pragma unroll
            for (int r = 0; r < 16; r++) s1c[r] = __builtin_amdgcn_exp2f(s1c[r]);
#pragma unroll
            for (int r = 0; r < 16; r++) s2c[r] = __builtin_amdgcn_exp2f(s2c[r]);
            lr0 += SUM16(s0c); lr1 += SUM16(s1c); lr2 += SUM16(s2c);

            // P -> bf16 A-fragments (cvt_pk + permlane32_swap), PV sharing each V-fragment read
            __builtin_amdgcn_s_setprio(1);
#pragma unroll
            for (int sh = 0; sh < 2; sh++) {
                const int off = sh * 8;
                bf16x8 pa0, pa1, pa2;
                {
                    unsigned A0, A1, B0, B1;
                    asm("v_cvt_pk_bf16_f32 %0, %1, %2" : "=v"(A0) : "v"(s0c[off + 0]), "v"(s0c[off + 1]));
                    asm("v_cvt_pk_bf16_f32 %0, %1, %2" : "=v"(A1) : "v"(s0c[off + 2]), "v"(s0c[off + 3]));
                    asm("v_cvt_pk_bf16_f32 %0, %1, %2" : "=v"(B0) : "v"(s0c[off + 4]), "v"(s0c[off + 5]));
                    asm("v_cvt_pk_bf16_f32 %0, %1, %2" : "=v"(B1) : "v"(s0c[off + 6]), "v"(s0c[off + 7]));
                    asm volatile("v_permlane32_swap_b32 %0, %1" : "+v"(A0), "+v"(B0));
                    asm volatile("v_permlane32_swap_b32 %0, %1" : "+v"(A1), "+v"(B1));
                    u32x4 fd = {A0, A1, B0, B1};
                    pa0 = __builtin_bit_cast(bf16x8, fd);
                }
                {
                    unsigned A0, A1, B0, B1;
                    asm("v_cvt_pk_bf16_f32 %0, %1, %2" : "=v"(A0) : "v"(s1c[off + 0]), "v"(s1c[off + 1]));
                    asm("v_cvt_pk_bf16_f32 %0, %1, %2" : "=v"(A1) : "v"(s1c[off + 2]), "v"(s1c[off + 3]));
                    asm("v_cvt_pk_bf16_f32 %0, %1, %2" : "=v"(B0) : "v"(s1c[off + 4]), "v"(s1c[off + 5]));
                    asm("v_cvt_pk_bf16_f32 %0, %1, %2" : "=v"(B1) : "v"(s1c[off + 6]), "v"(s1c[off + 7]));
                    asm volatile("v_permlane32_swap_b32 %0, %1" : "+v"(A0), "+v"(B0));
                    asm volatile("v_permlane32_swap_b32 %0, %1" : "+v"(A1), "+v"(B1));
                    u32x4 fd = {A0, A1, B0, B1};
                    pa1 = __builtin_bit_cast(bf16x8, fd);
                }
                {
                    unsigned A0, A1, B0, B1;
                    asm("v_cvt_pk_bf16_f32 %0, %1, %2" : "=v"(A0) : "v"(s2c[off + 0]), "v"(s2c[off + 1]));
                    asm("v_cvt_pk_bf16_f32 %0, %1, %2" : "=v"(A1) : "v"(s2c[off + 2]), "v"(s2c[off + 3]));
                    asm("v_cvt_pk_bf16_f32 %0, %1, %2" : "=v"(B0) : "v"(s2c[off + 4]), "v"(s2c[off + 5]));
                    asm("v_cvt_pk_bf16_f32 %0, %1, %2" : "=v"(B1) : "v"(s2c[off + 6]), "v"(s2c[off + 7]));
                    asm volatile("v_permlane32_swap_b32 %0, %1" : "+v"(A0), "+v"(B0));
                    asm volatile("v_permlane32_swap_b32 %0, %1" : "+v"(A1), "+v"(B1));
                    u32x4 fd = {A0, A1, B0, B1};
                    pa2 = __builtin_bit_cast(bf16x8, fd);
                }
                bf16x8 bv0 = *(const bf16x8*)(vb_ + (kvb * 2 + sh) * 2048);
                bf16x8 bv1 = *(const bf16x8*)(vb_ + (kvb * 2 + sh) * 2048 + 1024);
                acc[0][0] = __builtin_amdgcn_mfma_f32_32x32x16_bf16(pa0, bv0, acc[0][0], 0, 0, 0);
                acc[0][1] = __builtin_amdgcn_mfma_f32_32x32x16_bf16(pa0, bv1, acc[0][1], 0, 0, 0);
                acc[1][0] = __builtin_amdgcn_mfma_f32_32x32x16_bf16(pa1, bv0, acc[1][0], 0, 0, 0);
                acc[1][1] = __builtin_amdgcn_mfma_f32_32x32x16_bf16(pa1, bv1, acc[1][1], 0, 0, 0);
                acc[2][0] = __builtin_amdgcn_mfma_f32_32x32x16_bf16(pa2, bv0, acc[2][0], 0, 0, 0);
                acc[2][1] = __builtin_amdgcn_mfma_f32_32x32x16_bf16(pa2, bv1, acc[2][1], 0, 0, 0);
            }
            __builtin_amdgcn_s_setprio(0);
        }
        __syncthreads();
    }
#undef SUM16

    // finish cross-lane l
    lr0 += __shfl_xor(lr0, 32, 64);
    lr1 += __shfl_xor(lr1, 32, 64);
    lr2 += __shfl_xor(lr2, 32, 64);

    // -------- in-block combine of the two KV halves (pair = same qsub) --------
    if (half) {
        if (h2 == 0) {
            *(float*)(smem + 49152 + (qsub * 3 + 0) * 128 + l31 * 4) = lr0;
            *(float*)(smem + 49152 + (qsub * 3 + 1) * 128 + l31 * 4) = lr1;
            *(float*)(smem + 49152 + (qsub * 3 + 2) * 128 + l31 * 4) = lr2;
        }
#pragma unroll
        for (int u = 0; u < 3; u++)
#pragma unroll
            for (int k = 0; k < 2; k++)
#pragma unroll
                for (int pc = 0; pc < 4; pc++) {
                    float4 f;
                    f.x = acc[u][k][4 * pc + 0]; f.y = acc[u][k][4 * pc + 1];
                    f.z = acc[u][k][4 * pc + 2]; f.w = acc[u][k][4 * pc + 3];
                    *(float4*)(smem + qsub * 24576 + (u * 2 + k) * 4096 + pc * 1024 + lane * 16) = f;
                }
    }
    __syncthreads();
    if (!half) {
        float lt0 = lr0 + *(const float*)(smem + 49152 + (qsub * 3 + 0) * 128 + l31 * 4);
        float lt1 = lr1 + *(const float*)(smem + 49152 + (qsub * 3 + 1) * 128 + l31 * 4);
        float lt2 = lr2 + *(const float*)(smem + 49152 + (qsub * 3 + 2) * 128 + l31 * 4);
#pragma unroll
        for (int u = 0; u < 3; u++) {
            f32x16 po0, po1;
#pragma unroll
            for (int pc = 0; pc < 4; pc++) {
                float4 f0 = *(const float4*)(smem + qsub * 24576 + (u * 2 + 0) * 4096 + pc * 1024 + lane * 16);
                po0[4 * pc + 0] = f0.x; po0[4 * pc + 1] = f0.y; po0[4 * pc + 2] = f0.z; po0[4 * pc + 3] = f0.w;
                float4 f1 = *(const float4*)(smem + qsub * 24576 + (u * 2 + 1) * 4096 + pc * 1024 + lane * 16);
                po1[4 * pc + 0] = f1.x; po1[4 * pc + 1] = f1.y; po1[4 * pc + 2] = f1.z; po1[4 * pc + 3] = f1.w;
            }
            float ltu = (u == 0) ? lt0 : ((u == 1) ? lt1 : lt2);
#pragma unroll
            for (int r = 0; r < 16; r++) {
                int qc = (r & 3) + 8 * (r >> 2) + 4 * h2;
                float lv = __builtin_amdgcn_rcpf(__shfl(ltu, qc, 64));
                int row = s0 + qsub * 32 + qc;
                size_t basei = ((size_t)(b * 2048 + row) * 12 + hbase + u) * 64;
                ob[basei + l31]      = f2b((acc[u][0][r] + po0[r]) * lv);
                ob[basei + 32 + l31] = f2b((acc[u][1][r] + po1[r]) * lv);
            }
        }
    }
}

// ---------------- Output GEMM: 128x128 tile, gload_lds staging, + bias + residual ----------------
__global__ __launch_bounds__(256) void gemm_out(const unsigned short* __restrict__ A,
                                                const unsigned short* __restrict__ WoT,
                                                const float* __restrict__ bo,
                                                const float* __restrict__ resid,
                                                float* __restrict__ out) {
    __shared__ __align__(1024) char smem[65536];
    const int m0 = blockIdx.x * 128;
    const int n0 = blockIdx.y * 128;
    const int tid = threadIdx.x, lane = tid & 63, w = tid >> 6;
    const int wr = w >> 1, wc = w & 1;
    const int rl = lane >> 3, cl = lane & 7;
    const int scol = (cl * 16) ^ (rl << 4);

    const char* srcA0 = (const char*)A + (size_t)(m0 + w * 32 +  0 + rl) * 1536 + scol;
    const char* srcA1 = (const char*)A + (size_t)(m0 + w * 32 +  8 + rl) * 1536 + scol;
    const char* srcA2 = (const char*)A + (size_t)(m0 + w * 32 + 16 + rl) * 1536 + scol;
    const char* srcA3 = (const char*)A + (size_t)(m0 + w * 32 + 24 + rl) * 1536 + scol;
    const char* srcB0 = (const char*)WoT + (size_t)(n0 + w * 32 +  0 + rl) * 1536 + scol;
    const char* srcB1 = (const char*)WoT + (size_t)(n0 + w * 32 +  8 + rl) * 1536 + scol;
    const char* srcB2 = (const char*)WoT + (size_t)(n0 + w * 32 + 16 + rl) * 1536 + scol;
    const char* srcB3 = (const char*)WoT + (size_t)(n0 + w * 32 + 24 + rl) * 1536 + scol;
    const int cb = w * 4096;

    f32x4 acc[4][4];
#pragma unroll
    for (int m = 0; m < 4; m++)
#pragma unroll
        for (int n = 0; n < 4; n++) acc[m][n] = (f32x4){0.f, 0.f, 0.f, 0.f};

    gload16(smem + cb +    0, srcA0); gload16(smem + cb + 1024, srcA1);
    gload16(smem + cb + 2048, srcA2); gload16(smem + cb + 3072, srcA3);
    gload16(smem + 32768 + cb +    0, srcB0); gload16(smem + 32768 + cb + 1024, srcB1);
    gload16(smem + 32768 + cb + 2048, srcB2); gload16(smem + 32768 + cb + 3072, srcB3);
    __syncthreads();

    for (int t = 0; t < 12; ++t) {
        const int cur = t & 1;
        if (t < 11) {
            srcA0 += 128; srcA1 += 128; srcA2 += 128; srcA3 += 128;
            srcB0 += 128; srcB1 += 128; srcB2 += 128; srcB3 += 128;
            char* ab = smem + (cur ^ 1) * 16384 + cb;
            char* bb = smem + 32768 + (cur ^ 1) * 16384 + cb;
            gload16(ab +    0, srcA0); gload16(ab + 1024, srcA1);
            gload16(ab + 2048, srcA2); gload16(ab + 3072, srcA3);
            gload16(bb +    0, srcB0); gload16(bb + 1024, srcB1);
            gload16(bb + 2048, srcB2); gload16(bb + 3072, srcB3);
        }
        const char* Ab = smem + cur * 16384;
        const char* Bb = smem + 32768 + cur * 16384;
#pragma unroll
        for (int ks = 0; ks < 2; ks++) {
            bf16x8 a[4], b[4];
#pragma unroll
            for (int m = 0; m < 4; m++)
                a[m] = *(const bf16x8*)(Ab + SWZ(wr * 64 + m * 16 + (lane & 15), (lane >> 4) * 16 + ks * 64));
#pragma unroll
            for (int n = 0; n < 4; n++)
                b[n] = *(const bf16x8*)(Bb + SWZ(wc * 64 + n * 16 + (lane & 15), (lane >> 4) * 16 + ks * 64));
#pragma unroll
            for (int m = 0; m < 4; m++)
#pragma unroll
                for (int n = 0; n < 4; n++)
                    acc[m][n] = __builtin_amdgcn_mfma_f32_16x16x32_bf16(a[m], b[n], acc[m][n], 0, 0, 0);
        }
        __syncthreads();
    }
#pragma unroll
    for (int n = 0; n < 4; n++) {
        int col = n0 + wc * 64 + n * 16 + (lane & 15);
        float bs = bo[col];
#pragma unroll
        for (int m = 0; m < 4; m++) {
#pragma unroll
            for (int r = 0; r < 4; r++) {
                int row = m0 + wr * 64 + m * 16 + ((lane >> 4) << 2) + r;
                out[(size_t)row * 768 + col] = acc[m][n][r] + bs + resid[(size_t)row * 768 + col];
            }
        }
    }
}

extern "C" void kernel_launch(void* const* d_in, const int* in_sizes, int n_in,
                              void* d_out, int out_size, void* d_ws, size_t ws_size,
                              hipStream_t stream) {
    const float* hs    = (const float*)d_in[0];
    const float* Wq    = (const float*)d_in[1];
    const float* bq    = (const float*)d_in[2];
    const float* Wk    = (const float*)d_in[3];
    const float* bk    = (const float*)d_in[4];
    const float* Wv    = (const float*)d_in[5];
    const float* bv    = (const float*)d_in[6];
    const float* Wo    = (const float*)d_in[7];
    const float* bo    = (const float*)d_in[8];
    const float* gamma = (const float*)d_in[9];
    const float* beta  = (const float*)d_in[10];
    float* out = (float*)d_out;

    char* p = (char*)d_ws;
    unsigned short* hbuf  = (unsigned short*)p; p += (size_t)4096 * 768 * 2;  // LN out; reused as attn out
    unsigned short* qbuf  = (unsigned short*)p; p += (size_t)4096 * 768 * 2;
    unsigned short* kfbuf = (unsigned short*)p; p += (size_t)4096 * 256 * 2;  // K fragment layout
    unsigned short* vfbuf = (unsigned short*)p; p += (size_t)4096 * 256 * 2;  // V fragment layout
    unsigned short* WqT = (unsigned short*)p; p += (size_t)768 * 768 * 2;
    unsigned short* WkT = (unsigned short*)p; p += (size_t)256 * 768 * 2;
    unsigned short* WvT = (unsigned short*)p; p += (size_t)256 * 768 * 2;
    unsigned short* WoT = (unsigned short*)p; p += (size_t)768 * 768 * 2;
    unsigned short* obuf = hbuf;   // alias: hbuf dead after gemm_qkv

    ln_kernel<<<1024, 256, 0, stream>>>(hs, gamma, beta, hbuf);
    transw_kernel<<<dim3(12, 12, 4), 256, 0, stream>>>(Wq, Wk, Wv, Wo, WqT, WkT, WvT, WoT);
    gemm_qkv<<<dim3(32, 10), 256, 0, stream>>>(hbuf, WqT, WkT, WvT, bq, bk, bv, qbuf, kfbuf, vfbuf);
    flash4_kernel<<<dim3(32, 8), 256, 0, stream>>>(qbuf, kfbuf, vfbuf, obuf);
    gemm_out<<<dim3(32, 6), 256, 0, stream>>>(obuf, WoT, bo, hs, out);
}

// Round 10
// 90.241 us; speedup vs baseline: 1.0424x; 1.0424x over previous
//
#include <hip/hip_runtime.h>

typedef short bf16x8 __attribute__((ext_vector_type(8)));
typedef float f32x4 __attribute__((ext_vector_type(4)));
typedef float f32x16 __attribute__((ext_vector_type(16)));
typedef unsigned u32x4 __attribute__((ext_vector_type(4)));

#define SWZ(r, cb) ((((int)(r)) << 7) + (((int)(cb)) ^ ((((int)(r)) & 7) << 4)))

__device__ __forceinline__ unsigned short f2b(float f) {
    unsigned u = __builtin_bit_cast(unsigned, f);
    u = (u + 0x7FFFu + ((u >> 16) & 1u)) >> 16;
    return (unsigned short)u;
}
__device__ __forceinline__ float b2f(unsigned short h) {
    unsigned u = ((unsigned)h) << 16;
    return __builtin_bit_cast(float, u);
}
__device__ __forceinline__ void gload16(void* lds, const void* gsrc) {
    __builtin_amdgcn_global_load_lds((const __attribute__((address_space(1))) void*)gsrc,
                                     (__attribute__((address_space(3))) void*)lds, 16, 0, 0);
}

// ---------------- LayerNorm: one wave per token, H=768 ----------------
__global__ __launch_bounds__(256) void ln_kernel(const float* __restrict__ x,
                                                 const float* __restrict__ gamma,
                                                 const float* __restrict__ beta,
                                                 unsigned short* __restrict__ h) {
    int lane = threadIdx.x & 63, wv = threadIdx.x >> 6;
    int tok = blockIdx.x * 4 + wv;
    const float* xr = x + (size_t)tok * 768;
    float v[12];
#pragma unroll
    for (int c = 0; c < 3; c++) {
        float4 t = *(const float4*)(xr + c * 256 + lane * 4);
        v[c * 4 + 0] = t.x; v[c * 4 + 1] = t.y; v[c * 4 + 2] = t.z; v[c * 4 + 3] = t.w;
    }
    float s = 0.f;
#pragma unroll
    for (int j = 0; j < 12; j++) s += v[j];
#pragma unroll
    for (int m = 1; m < 64; m <<= 1) s += __shfl_xor(s, m, 64);
    float mu = s * (1.0f / 768.0f);
    float s2 = 0.f;
#pragma unroll
    for (int j = 0; j < 12; j++) { float d = v[j] - mu; s2 += d * d; }
#pragma unroll
    for (int m = 1; m < 64; m <<= 1) s2 += __shfl_xor(s2, m, 64);
    float rstd = 1.0f / sqrtf(s2 * (1.0f / 768.0f) + 1e-12f);
    unsigned short* hr = h + (size_t)tok * 768;
#pragma unroll
    for (int c = 0; c < 3; c++) {
        float4 g = *(const float4*)(gamma + c * 256 + lane * 4);
        float4 bt = *(const float4*)(beta + c * 256 + lane * 4);
        ushort4 o;
        o.x = f2b((v[c * 4 + 0] - mu) * rstd * g.x + bt.x);
        o.y = f2b((v[c * 4 + 1] - mu) * rstd * g.y + bt.y);
        o.z = f2b((v[c * 4 + 2] - mu) * rstd * g.z + bt.z);
        o.w = f2b((v[c * 4 + 3] - mu) * rstd * g.w + bt.w);
        *(ushort4*)(hr + c * 256 + lane * 4) = o;
    }
}

// ---------------- Weight transpose+convert: fp32 [K][N] -> bf16 [N][K], K=768 ----------------
__global__ __launch_bounds__(256) void transw_kernel(const float* __restrict__ Wq,
                                                     const float* __restrict__ Wk,
                                                     const float* __restrict__ Wv,
                                                     const float* __restrict__ Wo,
                                                     unsigned short* __restrict__ WqT,
                                                     unsigned short* __restrict__ WkT,
                                                     unsigned short* __restrict__ WvT,
                                                     unsigned short* __restrict__ WoT) {
    __shared__ float tile[64][65];
    const float* W; unsigned short* WT; int N;
    switch (blockIdx.z) {
        case 0:  W = Wq; WT = WqT; N = 768; break;
        case 1:  W = Wk; WT = WkT; N = 256; break;
        case 2:  W = Wv; WT = WvT; N = 256; break;
        default: W = Wo; WT = WoT; N = 768; break;
    }
    int n0 = blockIdx.x * 64, k0 = blockIdx.y * 64;
    if (n0 >= N) return;
    int t = threadIdx.x;
#pragma unroll
    for (int i = 0; i < 4; i++) {
        int kr = (t >> 4) + i * 16, nc = (t & 15) * 4;
        float4 f = *(const float4*)(W + (size_t)(k0 + kr) * N + n0 + nc);
        tile[kr][nc + 0] = f.x; tile[kr][nc + 1] = f.y;
        tile[kr][nc + 2] = f.z; tile[kr][nc + 3] = f.w;
    }
    __syncthreads();
#pragma unroll
    for (int i = 0; i < 2; i++) {
        int nr = (t >> 3) + i * 32, kc = (t & 7) * 8;
        bf16x8 o;
#pragma unroll
        for (int j = 0; j < 8; j++) o[j] = (short)f2b(tile[kc + j][nr]);
        *(bf16x8*)(WT + (size_t)(n0 + nr) * 768 + k0 + kc) = o;
    }
}

// ---- QKV GEMM: 128x128 tile, gload_lds dbuf; epilogue: Q plain, K+RoPE->kfrag, V->vfrag ----
__global__ __launch_bounds__(256) void gemm_qkv(const unsigned short* __restrict__ A,
                                                const unsigned short* __restrict__ WqT,
                                                const unsigned short* __restrict__ WkT,
                                                const unsigned short* __restrict__ WvT,
                                                const float* __restrict__ bq,
                                                const float* __restrict__ bk,
                                                const float* __restrict__ bv,
                                                unsigned short* __restrict__ qo,
                                                unsigned short* __restrict__ kfrag,
                                                unsigned short* __restrict__ vfrag) {
    __shared__ __align__(1024) char smem[65536];
    const int m0 = blockIdx.x * 128;
    const int n0 = blockIdx.y * 128;
    const unsigned short* WT; const float* bias; int c0;
    if (n0 < 768)       { WT = WqT + (size_t)n0 * 768;          bias = bq; c0 = n0;        }
    else if (n0 < 1024) { WT = WkT + (size_t)(n0 - 768) * 768;  bias = bk; c0 = n0 - 768;  }
    else                { WT = WvT + (size_t)(n0 - 1024) * 768; bias = bv; c0 = n0 - 1024; }
    const int tid = threadIdx.x, lane = tid & 63, w = tid >> 6;
    const int wr = w >> 1, wc = w & 1;
    const int l15 = lane & 15;
    const int rl = lane >> 3, cl = lane & 7;
    const int scol = (cl * 16) ^ (rl << 4);

    const char* srcA0 = (const char*)A  + (size_t)(m0 + w * 32 +  0 + rl) * 1536 + scol;
    const char* srcA1 = (const char*)A  + (size_t)(m0 + w * 32 +  8 + rl) * 1536 + scol;
    const char* srcA2 = (const char*)A  + (size_t)(m0 + w * 32 + 16 + rl) * 1536 + scol;
    const char* srcA3 = (const char*)A  + (size_t)(m0 + w * 32 + 24 + rl) * 1536 + scol;
    const char* srcB0 = (const char*)WT + (size_t)(w * 32 +  0 + rl) * 1536 + scol;
    const char* srcB1 = (const char*)WT + (size_t)(w * 32 +  8 + rl) * 1536 + scol;
    const char* srcB2 = (const char*)WT + (size_t)(w * 32 + 16 + rl) * 1536 + scol;
    const char* srcB3 = (const char*)WT + (size_t)(w * 32 + 24 + rl) * 1536 + scol;
    const int cb = w * 4096;

    f32x4 acc[4][4];
#pragma unroll
    for (int m = 0; m < 4; m++)
#pragma unroll
        for (int n = 0; n < 4; n++) acc[m][n] = (f32x4){0.f, 0.f, 0.f, 0.f};

    gload16(smem + cb +    0, srcA0); gload16(smem + cb + 1024, srcA1);
    gload16(smem + cb + 2048, srcA2); gload16(smem + cb + 3072, srcA3);
    gload16(smem + 32768 + cb +    0, srcB0); gload16(smem + 32768 + cb + 1024, srcB1);
    gload16(smem + 32768 + cb + 2048, srcB2); gload16(smem + 32768 + cb + 3072, srcB3);
    __syncthreads();

    for (int t = 0; t < 12; ++t) {
        const int cur = t & 1;
        if (t < 11) {
            srcA0 += 128; srcA1 += 128; srcA2 += 128; srcA3 += 128;
            srcB0 += 128; srcB1 += 128; srcB2 += 128; srcB3 += 128;
            char* ab = smem + (cur ^ 1) * 16384 + cb;
            char* bb = smem + 32768 + (cur ^ 1) * 16384 + cb;
            gload16(ab +    0, srcA0); gload16(ab + 1024, srcA1);
            gload16(ab + 2048, srcA2); gload16(ab + 3072, srcA3);
            gload16(bb +    0, srcB0); gload16(bb + 1024, srcB1);
            gload16(bb + 2048, srcB2); gload16(bb + 3072, srcB3);
        }
        const char* Ab = smem + cur * 16384;
        const char* Bb = smem + 32768 + cur * 16384;
#pragma unroll
        for (int ks = 0; ks < 2; ks++) {
            bf16x8 a[4], b[4];
#pragma unroll
            for (int m = 0; m < 4; m++)
                a[m] = *(const bf16x8*)(Ab + SWZ(wr * 64 + m * 16 + l15, (lane >> 4) * 16 + ks * 64));
#pragma unroll
            for (int n = 0; n < 4; n++)
                b[n] = *(const bf16x8*)(Bb + SWZ(wc * 64 + n * 16 + l15, (lane >> 4) * 16 + ks * 64));
#pragma unroll
            for (int m = 0; m < 4; m++)
#pragma unroll
                for (int n = 0; n < 4; n++)
                    acc[m][n] = __builtin_amdgcn_mfma_f32_16x16x32_bf16(a[m], b[n], acc[m][n], 0, 0, 0);
        }
        __syncthreads();
    }

    if (n0 >= 1024) {
        // V: bias + store into vfrag fragment layout
#pragma unroll
        for (int n = 0; n < 4; n++) {
            int col = c0 + wc * 64 + n * 16 + l15;
            float bs = bias[col];
            int g = col >> 6, d = col & 63;
            int hd = d >> 5, ld = d & 31;
#pragma unroll
            for (int m = 0; m < 4; m++) {
                int row = m0 + wr * 64 + m * 16 + ((lane >> 4) << 2);
                int bb2 = row >> 11, srow = row & 2047;
                int tt = srow >> 6, kvc = srow & 63;
                int s = kvc >> 4, hl = (kvc >> 3) & 1, j0 = kvc & 7;
                ushort4 o;
                o.x = f2b(acc[m][n][0] + bs); o.y = f2b(acc[m][n][1] + bs);
                o.z = f2b(acc[m][n][2] + bs); o.w = f2b(acc[m][n][3] + bs);
                *(ushort4*)((char*)vfrag + ((size_t)((bb2 * 4 + g) * 32 + tt)) * 8192 +
                            (2 * s + hd) * 1024 + (hl * 32 + ld) * 16 + j0 * 2) = o;
            }
        }
    } else if (n0 >= 768) {
        // K: bias + RoPE, store into kfrag fragment layout
#pragma unroll
        for (int n = 0; n < 2; n++) {
            int col = c0 + wc * 64 + n * 16 + l15;
            float bs1 = bias[col], bs2 = bias[col + 32];
            int g = col >> 6, i = col & 63;   // i < 32
            float freq = exp2f(-(float)i * (13.287712379549449f / 32.0f));
            int s = i >> 4, h2k = (i >> 3) & 1, j = i & 7;
            int laneoff = (h2k * 32 + 0) * 16 + j * 2;
#pragma unroll
            for (int m = 0; m < 4; m++) {
#pragma unroll
                for (int r = 0; r < 4; r++) {
                    int row = m0 + wr * 64 + m * 16 + ((lane >> 4) << 2) + r;
                    int bb2 = row >> 11, srow = row & 2047;
                    int tt = srow >> 6, kvr = srow & 63, hk = kvr >> 5, lkv = kvr & 31;
                    float sn, cs;
                    sincosf((float)srow * freq, &sn, &cs);
                    float x1 = acc[m][n][r] + bs1, x2 = acc[m][n + 2][r] + bs2;
                    size_t base = ((size_t)((bb2 * 4 + g) * 32 + tt)) * 8192 + laneoff + lkv * 16;
                    *(unsigned short*)((char*)kfrag + base + (2 * s + hk) * 1024)     = f2b(x1 * cs - x2 * sn);
                    *(unsigned short*)((char*)kfrag + base + (2 * s + 4 + hk) * 1024) = f2b(x1 * sn + x2 * cs);
                }
            }
        }
    } else {
        // Q: plain bias store (RoPE+scale applied in flash)
#pragma unroll
        for (int n = 0; n < 4; n++) {
            int col = c0 + wc * 64 + n * 16 + l15;
            float bs = bias[col];
#pragma unroll
            for (int m = 0; m < 4; m++) {
#pragma unroll
                for (int r = 0; r < 4; r++) {
                    int row = m0 + wr * 64 + m * 16 + ((lane >> 4) << 2) + r;
                    qo[(size_t)row * 768 + col] = f2b(acc[m][n][r] + bs);
                }
            }
        }
    }
}

// ---- Flash attention: 8 waves = 2 qsub x 4 KV-quarters, 3 heads/wave, static-C softmax ----
__global__ __launch_bounds__(512, 1) void flash8_kernel(const unsigned short* __restrict__ qb,
                                                        const unsigned short* __restrict__ kfrag,
                                                        const unsigned short* __restrict__ vfrag,
                                                        unsigned short* __restrict__ ob) {
    // smem: stream q (quarter): base q*32768; dbuf cur*16384; K @+0 (8KB), V @+8192 (8KB).
    // Reused after the loop as the combine buffer.
    __shared__ __align__(1024) char smem[131072];
    const int s0 = blockIdx.x * 64;
    const int bg = blockIdx.y, b = bg >> 2;
    const int tid = threadIdx.x, lane = tid & 63, w = tid >> 6;
    const int h2 = lane >> 5, l31 = lane & 31;
    const int quarter = w & 3, qsub = w >> 2;
    const int hbase = (bg & 3) * 3;

    // staging: wave (qsub=0,q) stages K chunks 0..7 of stream q; (qsub=1,q) stages V chunks 0..7
    const char* kf = (const char*)kfrag + (size_t)bg * 262144;
    const char* vf = (const char*)vfrag + (size_t)bg * 262144;
    const char* src0 = (qsub ? vf : kf) + (size_t)(quarter * 8) * 8192 + lane * 16;
    const int lds0 = quarter * 32768 + (qsub ? 8192 : 0);
    const char* srcs[8]; int ldss[8];
#pragma unroll
    for (int i = 0; i < 8; i++) { srcs[i] = src0 + i * 1024; ldss[i] = lds0 + i * 1024; }
#pragma unroll
    for (int i = 0; i < 8; i++) gload16(smem + ldss[i], srcs[i]);

    // Q for 3 heads: RoPE + 1/8*log2e scale in-register
    const int qrow = s0 + qsub * 32 + l31;
    bf16x8 qf[3][4];
    {
        const float SC = 0.125f * 1.4426950408889634f;
        float cs_[16], sn_[16];
#pragma unroll
        for (int s = 0; s < 2; s++)
#pragma unroll
            for (int j = 0; j < 8; j++) {
                int i = 16 * s + 8 * h2 + j;
                float freq = exp2f(-(float)i * (13.287712379549449f / 32.0f));
                sincosf((float)qrow * freq, &sn_[s * 8 + j], &cs_[s * 8 + j]);
            }
#pragma unroll
        for (int u = 0; u < 3; u++) {
            const unsigned short* qbase = qb + ((size_t)(b * 2048 + qrow) * 12 + hbase + u) * 64 + 8 * h2;
            bf16x8 q0 = *(const bf16x8*)(qbase);
            bf16x8 q1 = *(const bf16x8*)(qbase + 16);
            bf16x8 q2 = *(const bf16x8*)(qbase + 32);
            bf16x8 q3 = *(const bf16x8*)(qbase + 48);
#pragma unroll
            for (int j = 0; j < 8; j++) {
                float x1 = b2f((unsigned short)q0[j]), x2 = b2f((unsigned short)q2[j]);
                qf[u][0][j] = (short)f2b((x1 * cs_[j] - x2 * sn_[j]) * SC);
                qf[u][2][j] = (short)f2b((x1 * sn_[j] + x2 * cs_[j]) * SC);
                float y1 = b2f((unsigned short)q1[j]), y2 = b2f((unsigned short)q3[j]);
                qf[u][1][j] = (short)f2b((y1 * cs_[8 + j] - y2 * sn_[8 + j]) * SC);
                qf[u][3][j] = (short)f2b((y1 * sn_[8 + j] + y2 * cs_[8 + j]) * SC);
            }
        }
    }

    f32x16 acc[3][2], cinit;
#pragma unroll
    for (int u = 0; u < 3; u++)
#pragma unroll
        for (int k = 0; k < 2; k++)
#pragma unroll
            for (int r = 0; r < 16; r++) acc[u][k][r] = 0.f;
#pragma unroll
    for (int r = 0; r < 16; r++) cinit[r] = -24.0f;
    float lr[3] = {0.f, 0.f, 0.f};

    __syncthreads();

#define SUM16(V) (((((V)[0]+(V)[1])+((V)[2]+(V)[3]))+(((V)[4]+(V)[5])+((V)[6]+(V)[7]))) + \
                  ((((V)[8]+(V)[9])+((V)[10]+(V)[11]))+(((V)[12]+(V)[13])+((V)[14]+(V)[15]))))

    for (int t = 0; t < 8; ++t) {
        const int cur = t & 1;
        if (t < 7) {
            const int nb = (cur ^ 1) * 16384;
#pragma unroll
            for (int i = 0; i < 8; i++) { srcs[i] += 8192; gload16(smem + ldss[i] + nb, srcs[i]); }
        }
        const char* kb_ = smem + quarter * 32768 + cur * 16384 + lane * 16;
        const char* vb_ = kb_ + 8192;

#pragma unroll
        for (int kvb = 0; kvb < 2; kvb++) {
            // S - 24 = K x Q^T for 3 heads, sharing each K-fragment read
            f32x16 s0c, s1c, s2c;
            __builtin_amdgcn_s_setprio(1);
            {
                bf16x8 ak = *(const bf16x8*)(kb_ + kvb * 1024);
                s0c = __builtin_amdgcn_mfma_f32_32x32x16_bf16(ak, qf[0][0], cinit, 0, 0, 0);
                s1c = __builtin_amdgcn_mfma_f32_32x32x16_bf16(ak, qf[1][0], cinit, 0, 0, 0);
                s2c = __builtin_amdgcn_mfma_f32_32x32x16_bf16(ak, qf[2][0], cinit, 0, 0, 0);
            }
#pragma unroll
            for (int s = 1; s < 4; s++) {
                bf16x8 ak = *(const bf16x8*)(kb_ + s * 2048 + kvb * 1024);
                s0c = __builtin_amdgcn_mfma_f32_32x32x16_bf16(ak, qf[0][s], s0c, 0, 0, 0);
                s1c = __builtin_amdgcn_mfma_f32_32x32x16_bf16(ak, qf[1][s], s1c, 0, 0, 0);
                s2c = __builtin_amdgcn_mfma_f32_32x32x16_bf16(ak, qf[2][s], s2c, 0, 0, 0);
            }
            __builtin_amdgcn_s_setprio(0);

            // P = exp2(S-24); accumulate per-lane partial l
#pragma unroll
            for (int r = 0; r < 16; r++) s0c[r] = __builtin_amdgcn_exp2f(s0c[r]);
#pragma unroll
            for (int r = 0; r < 16; r++) s1c[r] = __builtin_amdgcn_exp2f(s1c[r]);
#pragma unroll
            for (int r = 0; r < 16; r++) s2c[r] = __builtin_amdgcn_exp2f(s2c[r]);
            lr[0] += SUM16(s0c); lr[1] += SUM16(s1c); lr[2] += SUM16(s2c);

            // P -> bf16 A-fragments (cvt_pk + permlane32_swap), PV sharing each V-fragment read
            __builtin_amdgcn_s_setprio(1);
#pragma unroll
            for (int sh = 0; sh < 2; sh++) {
                const int off = sh * 8;
                bf16x8 pa0, pa1, pa2;
                {
                    unsigned A0, A1, B0, B1;
                    asm("v_cvt_pk_bf16_f32 %0, %1, %2" : "=v"(A0) : "v"(s0c[off + 0]), "v"(s0c[off + 1]));
                    asm("v_cvt_pk_bf16_f32 %0, %1, %2" : "=v"(A1) : "v"(s0c[off + 2]), "v"(s0c[off + 3]));
                    asm("v_cvt_pk_bf16_f32 %0, %1, %2" : "=v"(B0) : "v"(s0c[off + 4]), "v"(s0c[off + 5]));
                    asm("v_cvt_pk_bf16_f32 %0, %1, %2" : "=v"(B1) : "v"(s0c[off + 6]), "v"(s0c[off + 7]));
                    asm volatile("v_permlane32_swap_b32 %0, %1" : "+v"(A0), "+v"(B0));
                    asm volatile("v_permlane32_swap_b32 %0, %1" : "+v"(A1), "+v"(B1));
                    u32x4 fd = {A0, A1, B0, B1};
                    pa0 = __builtin_bit_cast(bf16x8, fd);
                }
                {
                    unsigned A0, A1, B0, B1;
                    asm("v_cvt_pk_bf16_f32 %0, %1, %2" : "=v"(A0) : "v"(s1c[off + 0]), "v"(s1c[off + 1]));
                    asm("v_cvt_pk_bf16_f32 %0, %1, %2" : "=v"(A1) : "v"(s1c[off + 2]), "v"(s1c[off + 3]));
                    asm("v_cvt_pk_bf16_f32 %0, %1, %2" : "=v"(B0) : "v"(s1c[off + 4]), "v"(s1c[off + 5]));
                    asm("v_cvt_pk_bf16_f32 %0, %1, %2" : "=v"(B1) : "v"(s1c[off + 6]), "v"(s1c[off + 7]));
                    asm volatile("v_permlane32_swap_b32 %0, %1" : "+v"(A0), "+v"(B0));
                    asm volatile("v_permlane32_swap_b32 %0, %1" : "+v"(A1), "+v"(B1));
                    u32x4 fd = {A0, A1, B0, B1};
                    pa1 = __builtin_bit_cast(bf16x8, fd);
                }
                {
                    unsigned A0, A1, B0, B1;
                    asm("v_cvt_pk_bf16_f32 %0, %1, %2" : "=v"(A0) : "v"(s2c[off + 0]), "v"(s2c[off + 1]));
                    asm("v_cvt_pk_bf16_f32 %0, %1, %2" : "=v"(A1) : "v"(s2c[off + 2]), "v"(s2c[off + 3]));
                    asm("v_cvt_pk_bf16_f32 %0, %1, %2" : "=v"(B0) : "v"(s2c[off + 4]), "v"(s2c[off + 5]));
                    asm("v_cvt_pk_bf16_f32 %0, %1, %2" : "=v"(B1) : "v"(s2c[off + 6]), "v"(s2c[off + 7]));
                    asm volatile("v_permlane32_swap_b32 %0, %1" : "+v"(A0), "+v"(B0));
                    asm volatile("v_permlane32_swap_b32 %0, %1" : "+v"(A1), "+v"(B1));
                    u32x4 fd = {A0, A1, B0, B1};
                    pa2 = __builtin_bit_cast(bf16x8, fd);
                }
                bf16x8 bv0 = *(const bf16x8*)(vb_ + (kvb * 2 + sh) * 2048);
                bf16x8 bv1 = *(const bf16x8*)(vb_ + (kvb * 2 + sh) * 2048 + 1024);
                acc[0][0] = __builtin_amdgcn_mfma_f32_32x32x16_bf16(pa0, bv0, acc[0][0], 0, 0, 0);
                acc[0][1] = __builtin_amdgcn_mfma_f32_32x32x16_bf16(pa0, bv1, acc[0][1], 0, 0, 0);
                acc[1][0] = __builtin_amdgcn_mfma_f32_32x32x16_bf16(pa1, bv0, acc[1][0], 0, 0, 0);
                acc[1][1] = __builtin_amdgcn_mfma_f32_32x32x16_bf16(pa1, bv1, acc[1][1], 0, 0, 0);
                acc[2][0] = __builtin_amdgcn_mfma_f32_32x32x16_bf16(pa2, bv0, acc[2][0], 0, 0, 0);
                acc[2][1] = __builtin_amdgcn_mfma_f32_32x32x16_bf16(pa2, bv1, acc[2][1], 0, 0, 0);
            }
            __builtin_amdgcn_s_setprio(0);
        }
        __syncthreads();
    }
#undef SUM16

    // finish cross-lane l
    lr[0] += __shfl_xor(lr[0], 32, 64);
    lr[1] += __shfl_xor(lr[1], 32, 64);
    lr[2] += __shfl_xor(lr[2], 32, 64);

    // -------- combine across 4 quarters (pure sums, static-C): 2-round tree --------
    // Round 1: quarter 2 -> quarter 0, quarter 3 -> quarter 1
    if (quarter >= 2) {
        int slot = qsub * 2 + (quarter - 2);
#pragma unroll
        for (int u = 0; u < 3; u++)
#pragma unroll
            for (int k = 0; k < 2; k++)
#pragma unroll
                for (int pc = 0; pc < 4; pc++) {
                    float4 f;
                    f.x = acc[u][k][4 * pc + 0]; f.y = acc[u][k][4 * pc + 1];
                    f.z = acc[u][k][4 * pc + 2]; f.w = acc[u][k][4 * pc + 3];
                    *(float4*)(smem + slot * 24576 + (u * 2 + k) * 4096 + pc * 1024 + lane * 16) = f;
                }
        if (h2 == 0) {
#pragma unroll
            for (int u = 0; u < 3; u++)
                *(float*)(smem + 114688 + slot * 512 + u * 128 + l31 * 4) = lr[u];
        }
    }
    __syncthreads();
    if (quarter < 2) {
        int slot = qsub * 2 + quarter;
#pragma unroll
        for (int u = 0; u < 3; u++) {
#pragma unroll
            for (int k = 0; k < 2; k++)
#pragma unroll
                for (int pc = 0; pc < 4; pc++) {
                    float4 f = *(const float4*)(smem + slot * 24576 + (u * 2 + k) * 4096 + pc * 1024 + lane * 16);
                    acc[u][k][4 * pc + 0] += f.x; acc[u][k][4 * pc + 1] += f.y;
                    acc[u][k][4 * pc + 2] += f.z; acc[u][k][4 * pc + 3] += f.w;
                }
            lr[u] += *(const float*)(smem + 114688 + slot * 512 + u * 128 + l31 * 4);
        }
    }
    __syncthreads();
    // Round 2: quarter 1 -> quarter 0
    if (quarter == 1) {
#pragma unroll
        for (int u = 0; u < 3; u++)
#pragma unroll
            for (int k = 0; k < 2; k++)
#pragma unroll
                for (int pc = 0; pc < 4; pc++) {
                    float4 f;
                    f.x = acc[u][k][4 * pc + 0]; f.y = acc[u][k][4 * pc + 1];
                    f.z = acc[u][k][4 * pc + 2]; f.w = acc[u][k][4 * pc + 3];
                    *(float4*)(smem + qsub * 24576 + (u * 2 + k) * 4096 + pc * 1024 + lane * 16) = f;
                }
        if (h2 == 0) {
#pragma unroll
            for (int u = 0; u < 3; u++)
                *(float*)(smem + 114688 + 2048 + qsub * 512 + u * 128 + l31 * 4) = lr[u];
        }
    }
    __syncthreads();
    if (quarter == 0) {
#pragma unroll
        for (int u = 0; u < 3; u++) {
            f32x16 po0, po1;
#pragma unroll
            for (int pc = 0; pc < 4; pc++) {
                float4 f0 = *(const float4*)(smem + qsub * 24576 + (u * 2 + 0) * 4096 + pc * 1024 + lane * 16);
                po0[4 * pc + 0] = f0.x; po0[4 * pc + 1] = f0.y; po0[4 * pc + 2] = f0.z; po0[4 * pc + 3] = f0.w;
                float4 f1 = *(const float4*)(smem + qsub * 24576 + (u * 2 + 1) * 4096 + pc * 1024 + lane * 16);
                po1[4 * pc + 0] = f1.x; po1[4 * pc + 1] = f1.y; po1[4 * pc + 2] = f1.z; po1[4 * pc + 3] = f1.w;
            }
            float ltu = lr[u] + *(const float*)(smem + 114688 + 2048 + qsub * 512 + u * 128 + l31 * 4);
#pragma unroll
            for (int r = 0; r < 16; r++) {
                int qc = (r & 3) + 8 * (r >> 2) + 4 * h2;
                float lv = __builtin_amdgcn_rcpf(__shfl(ltu, qc, 64));
                int row = s0 + qsub * 32 + qc;
                size_t basei = ((size_t)(b * 2048 + row) * 12 + hbase + u) * 64;
                ob[basei + l31]      = f2b((acc[u][0][r] + po0[r]) * lv);
                ob[basei + 32 + l31] = f2b((acc[u][1][r] + po1[r]) * lv);
            }
        }
    }
}

// ---------------- Output GEMM: 128x128 tile, gload_lds staging, + bias + residual ----------------
__global__ __launch_bounds__(256) void gemm_out(const unsigned short* __restrict__ A,
                                                const unsigned short* __restrict__ WoT,
                                                const float* __restrict__ bo,
                                                const float* __restrict__ resid,
                                                float* __restrict__ out) {
    __shared__ __align__(1024) char smem[65536];
    const int m0 = blockIdx.x * 128;
    const int n0 = blockIdx.y * 128;
    const int tid = threadIdx.x, lane = tid & 63, w = tid >> 6;
    const int wr = w >> 1, wc = w & 1;
    const int rl = lane >> 3, cl = lane & 7;
    const int scol = (cl * 16) ^ (rl << 4);

    const char* srcA0 = (const char*)A + (size_t)(m0 + w * 32 +  0 + rl) * 1536 + scol;
    const char* srcA1 = (const char*)A + (size_t)(m0 + w * 32 +  8 + rl) * 1536 + scol;
    const char* srcA2 = (const char*)A + (size_t)(m0 + w * 32 + 16 + rl) * 1536 + scol;
    const char* srcA3 = (const char*)A + (size_t)(m0 + w * 32 + 24 + rl) * 1536 + scol;
    const char* srcB0 = (const char*)WoT + (size_t)(n0 + w * 32 +  0 + rl) * 1536 + scol;
    const char* srcB1 = (const char*)WoT + (size_t)(n0 + w * 32 +  8 + rl) * 1536 + scol;
    const char* srcB2 = (const char*)WoT + (size_t)(n0 + w * 32 + 16 + rl) * 1536 + scol;
    const char* srcB3 = (const char*)WoT + (size_t)(n0 + w * 32 + 24 + rl) * 1536 + scol;
    const int cb = w * 4096;

    f32x4 acc[4][4];
#pragma unroll
    for (int m = 0; m < 4; m++)
#pragma unroll
        for (int n = 0; n < 4; n++) acc[m][n] = (f32x4){0.f, 0.f, 0.f, 0.f};

    gload16(smem + cb +    0, srcA0); gload16(smem + cb + 1024, srcA1);
    gload16(smem + cb + 2048, srcA2); gload16(smem + cb + 3072, srcA3);
    gload16(smem + 32768 + cb +    0, srcB0); gload16(smem + 32768 + cb + 1024, srcB1);
    gload16(smem + 32768 + cb + 2048, srcB2); gload16(smem + 32768 + cb + 3072, srcB3);
    __syncthreads();

    for (int t = 0; t < 12; ++t) {
        const int cur = t & 1;
        if (t < 11) {
            srcA0 += 128; srcA1 += 128; srcA2 += 128; srcA3 += 128;
            srcB0 += 128; srcB1 += 128; srcB2 += 128; srcB3 += 128;
            char* ab = smem + (cur ^ 1) * 16384 + cb;
            char* bb = smem + 32768 + (cur ^ 1) * 16384 + cb;
            gload16(ab +    0, srcA0); gload16(ab + 1024, srcA1);
            gload16(ab + 2048, srcA2); gload16(ab + 3072, srcA3);
            gload16(bb +    0, srcB0); gload16(bb + 1024, srcB1);
            gload16(bb + 2048, srcB2); gload16(bb + 3072, srcB3);
        }
        const char* Ab = smem + cur * 16384;
        const char* Bb = smem + 32768 + cur * 16384;
#pragma unroll
        for (int ks = 0; ks < 2; ks++) {
            bf16x8 a[4], b[4];
#pragma unroll
            for (int m = 0; m < 4; m++)
                a[m] = *(const bf16x8*)(Ab + SWZ(wr * 64 + m * 16 + (lane & 15), (lane >> 4) * 16 + ks * 64));
#pragma unroll
            for (int n = 0; n < 4; n++)
                b[n] = *(const bf16x8*)(Bb + SWZ(wc * 64 + n * 16 + (lane & 15), (lane >> 4) * 16 + ks * 64));
#pragma unroll
            for (int m = 0; m < 4; m++)
#pragma unroll
                for (int n = 0; n < 4; n++)
                    acc[m][n] = __builtin_amdgcn_mfma_f32_16x16x32_bf16(a[m], b[n], acc[m][n], 0, 0, 0);
        }
        __syncthreads();
    }
#pragma unroll
    for (int n = 0; n < 4; n++) {
        int col = n0 + wc * 64 + n * 16 + (lane & 15);
        float bs = bo[col];
#pragma unroll
        for (int m = 0; m < 4; m++) {
#pragma unroll
            for (int r = 0; r < 4; r++) {
                int row = m0 + wr * 64 + m * 16 + ((lane >> 4) << 2) + r;
                out[(size_t)row * 768 + col] = acc[m][n][r] + bs + resid[(size_t)row * 768 + col];
            }
        }
    }
}

extern "C" void kernel_launch(void* const* d_in, const int* in_sizes, int n_in,
                              void* d_out, int out_size, void* d_ws, size_t ws_size,
                              hipStream_t stream) {
    const float* hs    = (const float*)d_in[0];
    const float* Wq    = (const float*)d_in[1];
    const float* bq    = (const float*)d_in[2];
    const float* Wk    = (const float*)d_in[3];
    const float* bk    = (const float*)d_in[4];
    const float* Wv    = (const float*)d_in[5];
    const float* bv    = (const float*)d_in[6];
    const float* Wo    = (const float*)d_in[7];
    const float* bo    = (const float*)d_in[8];
    const float* gamma = (const float*)d_in[9];
    const float* beta  = (const float*)d_in[10];
    float* out = (float*)d_out;

    char* p = (char*)d_ws;
    unsigned short* hbuf  = (unsigned short*)p; p += (size_t)4096 * 768 * 2;  // LN out; reused as attn out
    unsigned short* qbuf  = (unsigned short*)p; p += (size_t)4096 * 768 * 2;
    unsigned short* kfbuf = (unsigned short*)p; p += (size_t)4096 * 256 * 2;  // K fragment layout
    unsigned short* vfbuf = (unsigned short*)p; p += (size_t)4096 * 256 * 2;  // V fragment layout
    unsigned short* WqT = (unsigned short*)p; p += (size_t)768 * 768 * 2;
    unsigned short* WkT = (unsigned short*)p; p += (size_t)256 * 768 * 2;
    unsigned short* WvT = (unsigned short*)p; p += (size_t)256 * 768 * 2;
    unsigned short* WoT = (unsigned short*)p; p += (size_t)768 * 768 * 2;
    unsigned short* obuf = hbuf;   // alias: hbuf dead after gemm_qkv

    ln_kernel<<<1024, 256, 0, stream>>>(hs, gamma, beta, hbuf);
    transw_kernel<<<dim3(12, 12, 4), 256, 0, stream>>>(Wq, Wk, Wv, Wo, WqT, WkT, WvT, WoT);
    gemm_qkv<<<dim3(32, 10), 256, 0, stream>>>(hbuf, WqT, WkT, WvT, bq, bk, bv, qbuf, kfbuf, vfbuf);
    flash8_kernel<<<dim3(32, 8), 512, 0, stream>>>(qbuf, kfbuf, vfbuf, obuf);
    gemm_out<<<dim3(32, 6), 256, 0, stream>>>(obuf, WoT, bo, hs, out);
}